// Round 4
// baseline (170.896 us; speedup 1.0000x reference)
//
#include <hip/hip_runtime.h>

#define NL   128   // rows per line table
#define CL   32    // channels per line table
#define HDIM 128   // hidden dim
#define GRID1 1024 // blocks

// ws layout (u64): [0..5] gmask {x_lo,x_hi,y_lo,y_hi,z_lo,z_hi}, [6] done-counter.
// kernel_launch memsets the first 64 bytes to 0 each call.

__global__ __launch_bounds__(256) void fused_kernel(
    const float* __restrict__ coords, long long nflt,
    const float* __restrict__ l0, const float* __restrict__ l1,
    const float* __restrict__ l2,
    const float* __restrict__ w1, const float* __restrict__ b1,
    const float* __restrict__ w2, const float* __restrict__ b2,
    unsigned long long* __restrict__ gws,
    float* __restrict__ out, int out_n)
{
    const int tid = threadIdx.x;
    const int gid = blockIdx.x * blockDim.x + tid;
    const int nthreads = gridDim.x * blockDim.x;
    const int lane = tid & 63;
    const int wave = tid >> 6;

    // ---- Phase 1: occupancy-mask partials over all coords ----
    unsigned long long mx0 = 0, mx1 = 0, my0 = 0, my1 = 0, mz0 = 0, mz1 = 0;

    const float4* c4 = (const float4*)coords;
    const long long n4 = nflt >> 2;
    const long long n4tri = (n4 / 3) * 3;

    // 3 consecutive float4s per thread per iter => element dim e%3 is static.
    for (long long base = (long long)gid * 3; base + 2 < n4tri;
         base += (long long)nthreads * 3) {
        float4 a = c4[base + 0];
        float4 b = c4[base + 1];
        float4 c = c4[base + 2];
        float v[12] = {a.x, a.y, a.z, a.w, b.x, b.y, b.z, b.w, c.x, c.y, c.z, c.w};
        #pragma unroll
        for (int e = 0; e < 12; ++e) {
            float fi = rintf((v[e] + 2.0f) * 32.0f);   // (x+D/2)*(Nl/D), half-even
            bool valid = (fi >= 0.0f) && (fi < 128.0f);
            int idx = (int)fi;
            unsigned long long bit = 1ull << (idx & 63);
            unsigned long long blo = (valid && idx < 64) ? bit : 0ull;
            unsigned long long bhi = (valid && idx >= 64) ? bit : 0ull;
            if (e % 3 == 0)      { mx0 |= blo; mx1 |= bhi; }
            else if (e % 3 == 1) { my0 |= blo; my1 |= bhi; }
            else                 { mz0 |= blo; mz1 |= bhi; }
        }
    }
    for (long long f = n4tri * 4 + gid; f < nflt; f += nthreads) {  // tail (unused here)
        float fi = rintf((coords[f] + 2.0f) * 32.0f);
        bool valid = (fi >= 0.0f) && (fi < 128.0f);
        int idx = (int)fi;
        unsigned long long bit = 1ull << (idx & 63);
        unsigned long long blo = (valid && idx < 64) ? bit : 0ull;
        unsigned long long bhi = (valid && idx >= 64) ? bit : 0ull;
        int d = (int)(f % 3);
        if (d == 0)      { mx0 |= blo; mx1 |= bhi; }
        else if (d == 1) { my0 |= blo; my1 |= bhi; }
        else             { mz0 |= blo; mz1 |= bhi; }
    }

    #pragma unroll
    for (int off = 1; off < 64; off <<= 1) {
        mx0 |= __shfl_xor(mx0, off);
        mx1 |= __shfl_xor(mx1, off);
        my0 |= __shfl_xor(my0, off);
        my1 |= __shfl_xor(my1, off);
        mz0 |= __shfl_xor(mz0, off);
        mz1 |= __shfl_xor(mz1, off);
    }

    __shared__ unsigned long long sm[4][6];
    if (lane == 0) {
        sm[wave][0] = mx0; sm[wave][1] = mx1;
        sm[wave][2] = my0; sm[wave][3] = my1;
        sm[wave][4] = mz0; sm[wave][5] = mz1;
    }
    __syncthreads();
    if (tid < 6) {
        // 6 distinct addresses x 1024 blocks: pipelined at the coherent point.
        unsigned long long r = sm[0][tid] | sm[1][tid] | sm[2][tid] | sm[3][tid];
        atomicOr(&gws[tid], r);
    }

    // ---- Constant for rows >= NL, and fill out[NL..out_n) ----
    float p = fmaxf(b1[lane], 0.0f) * w2[lane]
            + fmaxf(b1[lane + 64], 0.0f) * w2[lane + 64];
    #pragma unroll
    for (int off = 1; off < 64; off <<= 1) p += __shfl_xor(p, off);
    const float constant = p + b2[0];

    const int n4o = (out_n - NL) >> 2;
    float4* o4 = (float4*)(out + NL);
    const float4 cv = make_float4(constant, constant, constant, constant);
    for (int i = gid; i < n4o; i += nthreads) o4[i] = cv;
    for (int i = NL + (n4o << 2) + gid; i < out_n; i += nthreads) out[i] = constant;

    // ---- Arrival: last block runs the head ----
    __shared__ int isLast;
    __syncthreads();
    if (tid == 0) {
        // threadfence drains this wave's in-flight atomicOr (lanes 0..5 are in
        // wave 0 with tid 0) and orders it before the counter bump.
        __threadfence();
        unsigned long long old = atomicAdd(&gws[6], 1ull);
        isLast = (old == (unsigned long long)(gridDim.x - 1)) ? 1 : 0;
    }
    __syncthreads();
    if (!isLast) return;

    // ---- Head (single block, 256 threads): out[r] for r in 0..127 ----
    __shared__ unsigned long long smG[6];
    if (tid < 6) smG[tid] = atomicOr(&gws[tid], 0ull);   // coherent read
    __syncthreads();

    const int r = tid >> 1;     // 0..127
    const int g = tid & 1;      // which half of hidden units
    const int word = r >> 6;
    const int bit = r & 63;
    const float ox = (float)((smG[0 + word] >> bit) & 1ull);
    const float oy = (float)((smG[2 + word] >> bit) & 1ull);
    const float oz = (float)((smG[4 + word] >> bit) & 1ull);

    const float R  = 0.4f;
    const float R2 = (float)(0.4 * 0.4);

    float feats[CL];
    const float4* l0v = (const float4*)(l0 + r * CL);
    const float4* l1v = (const float4*)(l1 + r * CL);
    const float4* l2v = (const float4*)(l2 + r * CL);
    #pragma unroll
    for (int q4 = 0; q4 < CL / 4; ++q4) {
        float4 a = l0v[q4];
        float4 b = l1v[q4];
        float4 c = l2v[q4];
        float xs[4] = {a.x * ox, a.y * ox, a.z * ox, a.w * ox};
        float ys[4] = {b.x * oy, b.y * oy, b.z * oy, b.w * oy};
        float zs[4] = {c.x * oz, c.y * oz, c.z * oz, c.w * oz};
        #pragma unroll
        for (int q = 0; q < 4; ++q) {
            float x = xs[q], y = ys[q], z = zs[q];
            feats[q4 * 4 + q] = (x + y + z)
                              + (x * y + x * z + y * z) / R
                              + x * y * z / R2;
        }
    }

    float partial = 0.0f;
    #pragma unroll 4
    for (int jj = 0; jj < HDIM / 2; ++jj) {
        const int j = g * (HDIM / 2) + jj;
        const float4* w1v = (const float4*)(w1 + j * CL);
        float acc = b1[j];
        #pragma unroll
        for (int q4 = 0; q4 < CL / 4; ++q4) {
            float4 w = w1v[q4];
            acc += feats[q4 * 4 + 0] * w.x;
            acc += feats[q4 * 4 + 1] * w.y;
            acc += feats[q4 * 4 + 2] * w.z;
            acc += feats[q4 * 4 + 3] * w.w;
        }
        partial += fmaxf(acc, 0.0f) * w2[j];
    }
    partial += __shfl_xor(partial, 1);   // pair (2r, 2r+1) are adjacent lanes
    if (g == 0) out[r] = partial + b2[0];
}

extern "C" void kernel_launch(void* const* d_in, const int* in_sizes, int n_in,
                              void* d_out, int out_size, void* d_ws, size_t ws_size,
                              hipStream_t stream) {
    const float* coords = (const float*)d_in[0];
    const float* l0 = (const float*)d_in[1];
    const float* l1 = (const float*)d_in[2];
    const float* l2 = (const float*)d_in[3];
    const float* w1 = (const float*)d_in[4];
    const float* b1 = (const float*)d_in[5];
    const float* w2 = (const float*)d_in[6];
    const float* b2 = (const float*)d_in[7];
    float* out = (float*)d_out;
    unsigned long long* gws = (unsigned long long*)d_ws;
    const long long nflt = (long long)in_sizes[0];

    hipMemsetAsync(d_ws, 0, 64, stream);   // gmask[6] + counter
    fused_kernel<<<GRID1, 256, 0, stream>>>(coords, nflt, l0, l1, l2,
                                            w1, b1, w2, b2, gws, out, out_size);
}

// Round 5
// 159.109 us; speedup vs baseline: 1.0741x; 1.0741x over previous
//
#include <hip/hip_runtime.h>

#define NL   128   // rows per line table
#define CL   32    // channels per line table
#define HDIM 128   // hidden dim
#define GRID1 1024 // blocks

// ws layout (u64): [0..5] gmask {x_lo,x_hi,y_lo,y_hi,z_lo,z_hi}, [6] done-counter.
// kernel_launch memsets the first 64 bytes to 0 each call.
// NO __threadfence anywhere: cross-block comms are atomics-only (device-coherent
// point); per-block ordering Or->Add is enforced with s_waitcnt vmcnt(0), which
// waits for the wave's own VMEM acks without the L2 writeback/invalidate that
// made round 4's __threadfence cost ~87 us across 1024 blocks.

__global__ __launch_bounds__(256) void fused_kernel(
    const float* __restrict__ coords, long long nflt,
    const float* __restrict__ l0, const float* __restrict__ l1,
    const float* __restrict__ l2,
    const float* __restrict__ w1, const float* __restrict__ b1,
    const float* __restrict__ w2, const float* __restrict__ b2,
    unsigned long long* __restrict__ gws,
    float* __restrict__ out, int out_n)
{
    const int tid = threadIdx.x;
    const int gid = blockIdx.x * blockDim.x + tid;
    const int nthreads = gridDim.x * blockDim.x;
    const int lane = tid & 63;
    const int wave = tid >> 6;

    // ---- Phase 1: occupancy-mask partials over all coords ----
    unsigned long long mx0 = 0, mx1 = 0, my0 = 0, my1 = 0, mz0 = 0, mz1 = 0;

    const float4* c4 = (const float4*)coords;
    const long long n4 = nflt >> 2;
    const long long n4tri = (n4 / 3) * 3;

    // 3 consecutive float4s per thread per iter => element dim e%3 is static.
    for (long long base = (long long)gid * 3; base + 2 < n4tri;
         base += (long long)nthreads * 3) {
        float4 a = c4[base + 0];
        float4 b = c4[base + 1];
        float4 c = c4[base + 2];
        float v[12] = {a.x, a.y, a.z, a.w, b.x, b.y, b.z, b.w, c.x, c.y, c.z, c.w};
        #pragma unroll
        for (int e = 0; e < 12; ++e) {
            float fi = rintf((v[e] + 2.0f) * 32.0f);   // (x+D/2)*(Nl/D), half-even
            bool valid = (fi >= 0.0f) && (fi < 128.0f);
            int idx = (int)fi;
            unsigned long long bit = 1ull << (idx & 63);
            unsigned long long blo = (valid && idx < 64) ? bit : 0ull;
            unsigned long long bhi = (valid && idx >= 64) ? bit : 0ull;
            if (e % 3 == 0)      { mx0 |= blo; mx1 |= bhi; }
            else if (e % 3 == 1) { my0 |= blo; my1 |= bhi; }
            else                 { mz0 |= blo; mz1 |= bhi; }
        }
    }
    for (long long f = n4tri * 4 + gid; f < nflt; f += nthreads) {  // tail (unused here)
        float fi = rintf((coords[f] + 2.0f) * 32.0f);
        bool valid = (fi >= 0.0f) && (fi < 128.0f);
        int idx = (int)fi;
        unsigned long long bit = 1ull << (idx & 63);
        unsigned long long blo = (valid && idx < 64) ? bit : 0ull;
        unsigned long long bhi = (valid && idx >= 64) ? bit : 0ull;
        int d = (int)(f % 3);
        if (d == 0)      { mx0 |= blo; mx1 |= bhi; }
        else if (d == 1) { my0 |= blo; my1 |= bhi; }
        else             { mz0 |= blo; mz1 |= bhi; }
    }

    #pragma unroll
    for (int off = 1; off < 64; off <<= 1) {
        mx0 |= __shfl_xor(mx0, off);
        mx1 |= __shfl_xor(mx1, off);
        my0 |= __shfl_xor(my0, off);
        my1 |= __shfl_xor(my1, off);
        mz0 |= __shfl_xor(mz0, off);
        mz1 |= __shfl_xor(mz1, off);
    }

    __shared__ unsigned long long sm[4][6];
    if (lane == 0) {
        sm[wave][0] = mx0; sm[wave][1] = mx1;
        sm[wave][2] = my0; sm[wave][3] = my1;
        sm[wave][4] = mz0; sm[wave][5] = mz1;
    }
    __syncthreads();
    if (tid < 6) {
        // 6 distinct coherent-point addresses x 1024 blocks (round 1 showed
        // this pattern completes fast).
        unsigned long long r = sm[0][tid] | sm[1][tid] | sm[2][tid] | sm[3][tid];
        atomicOr(&gws[tid], r);
    }

    // ---- Constant for rows >= NL, and fill out[NL..out_n) ----
    float p = fmaxf(b1[lane], 0.0f) * w2[lane]
            + fmaxf(b1[lane + 64], 0.0f) * w2[lane + 64];
    #pragma unroll
    for (int off = 1; off < 64; off <<= 1) p += __shfl_xor(p, off);
    const float constant = p + b2[0];

    const int n4o = (out_n - NL) >> 2;
    float4* o4 = (float4*)(out + NL);
    const float4 cv = make_float4(constant, constant, constant, constant);
    for (int i = gid; i < n4o; i += nthreads) o4[i] = cv;
    for (int i = NL + (n4o << 2) + gid; i < out_n; i += nthreads) out[i] = constant;

    // ---- Arrival: last block runs the head ----
    __shared__ int isLast;
    __syncthreads();
    if (tid == 0) {
        // Lanes 0..5 (the atomicOr issuers) are in THIS wave; vmcnt(0) waits
        // for their acks at the coherent point. No cache writeback needed.
        asm volatile("s_waitcnt vmcnt(0)" ::: "memory");
        unsigned long long old = atomicAdd(&gws[6], 1ull);
        isLast = (old == (unsigned long long)(gridDim.x - 1)) ? 1 : 0;
    }
    __syncthreads();
    if (!isLast) return;

    // ---- Head (single block, 256 threads): out[r] for r in 0..127 ----
    __shared__ unsigned long long smG[6];
    if (tid < 6) smG[tid] = atomicOr(&gws[tid], 0ull);   // coherent RMW read
    __syncthreads();

    const int r = tid >> 1;     // 0..127
    const int g = tid & 1;      // which half of hidden units
    const int word = r >> 6;
    const int bit = r & 63;
    const float ox = (float)((smG[0 + word] >> bit) & 1ull);
    const float oy = (float)((smG[2 + word] >> bit) & 1ull);
    const float oz = (float)((smG[4 + word] >> bit) & 1ull);

    const float R  = 0.4f;
    const float R2 = (float)(0.4 * 0.4);

    float feats[CL];
    const float4* l0v = (const float4*)(l0 + r * CL);
    const float4* l1v = (const float4*)(l1 + r * CL);
    const float4* l2v = (const float4*)(l2 + r * CL);
    #pragma unroll
    for (int q4 = 0; q4 < CL / 4; ++q4) {
        float4 a = l0v[q4];
        float4 b = l1v[q4];
        float4 c = l2v[q4];
        float xs[4] = {a.x * ox, a.y * ox, a.z * ox, a.w * ox};
        float ys[4] = {b.x * oy, b.y * oy, b.z * oy, b.w * oy};
        float zs[4] = {c.x * oz, c.y * oz, c.z * oz, c.w * oz};
        #pragma unroll
        for (int q = 0; q < 4; ++q) {
            float x = xs[q], y = ys[q], z = zs[q];
            feats[q4 * 4 + q] = (x + y + z)
                              + (x * y + x * z + y * z) / R
                              + x * y * z / R2;
        }
    }

    float partial = 0.0f;
    #pragma unroll 4
    for (int jj = 0; jj < HDIM / 2; ++jj) {
        const int j = g * (HDIM / 2) + jj;
        const float4* w1v = (const float4*)(w1 + j * CL);
        float acc = b1[j];
        #pragma unroll
        for (int q4 = 0; q4 < CL / 4; ++q4) {
            float4 w = w1v[q4];
            acc += feats[q4 * 4 + 0] * w.x;
            acc += feats[q4 * 4 + 1] * w.y;
            acc += feats[q4 * 4 + 2] * w.z;
            acc += feats[q4 * 4 + 3] * w.w;
        }
        partial += fmaxf(acc, 0.0f) * w2[j];
    }
    partial += __shfl_xor(partial, 1);   // pair (2r, 2r+1) are adjacent lanes
    if (g == 0) out[r] = partial + b2[0];
}

extern "C" void kernel_launch(void* const* d_in, const int* in_sizes, int n_in,
                              void* d_out, int out_size, void* d_ws, size_t ws_size,
                              hipStream_t stream) {
    const float* coords = (const float*)d_in[0];
    const float* l0 = (const float*)d_in[1];
    const float* l1 = (const float*)d_in[2];
    const float* l2 = (const float*)d_in[3];
    const float* w1 = (const float*)d_in[4];
    const float* b1 = (const float*)d_in[5];
    const float* w2 = (const float*)d_in[6];
    const float* b2 = (const float*)d_in[7];
    float* out = (float*)d_out;
    unsigned long long* gws = (unsigned long long*)d_ws;
    const long long nflt = (long long)in_sizes[0];

    hipMemsetAsync(d_ws, 0, 64, stream);   // gmask[6] + counter
    fused_kernel<<<GRID1, 256, 0, stream>>>(coords, nflt, l0, l1, l2,
                                            w1, b1, w2, b2, gws, out, out_size);
}